// Round 6
// baseline (306.910 us; speedup 1.0000x reference)
//
#include <hip/hip_runtime.h>

// emb-lookup -> LSTM(64) over T=512 -> Dense(3) -> softmax.  512 blocks x 256 thr.
// Quad = one hidden unit's 4 gate cols (i,f,g,o). Lane j of quad: k-slice
// [16j,16j+16) of h (4 x ds_read_b128 broadcast), partial dots for all 4 gate
// cols via v_pk_fma_f32, quad allreduce + gate broadcast via DPP quad_perm.
// x-projection (+bias) precomputed as table[VOCAB][256] in d_ws, prefetched 2
// steps ahead. Weights held via in-loop asm pin (R4: 241us). NEW vs R4: the
// per-step barrier is `s_waitcnt lgkmcnt(0); s_barrier` ONLY -- __syncthreads
// emits vmcnt(0) and drained the 2-step table prefetch every iteration
// (L2/L3 latency ~300-400cyc exposed per step). NOTE (R5): v_pk_fma_f32
// cannot take AGPR sources on gfx950 -- "a"-constraint operands don't encode.

#define VOCAB 50000
#define EMB 32
#define HID 64
#define NCLS 3
#define BATCH 512
#define TSEQ 512
#define FOURH 256
#define LOG2E 1.4426950408889634f

typedef float v2f __attribute__((ext_vector_type(2)));

#define DPP_XOR1 0xB1  // quad_perm [1,0,3,2]
#define DPP_XOR2 0x4E  // quad_perm [2,3,0,1]
#define DPP_BC0  0x00
#define DPP_BC1  0x55
#define DPP_BC2  0xAA
#define DPP_BC3  0xFF

template <int CTRL>
__device__ __forceinline__ float dpp_mov(float x) {
    int y = __builtin_amdgcn_mov_dpp(__builtin_bit_cast(int, x), CTRL, 0xF, 0xF, true);
    return __builtin_bit_cast(float, y);
}
__device__ __forceinline__ float qred(float p) {
    p += dpp_mov<DPP_XOR1>(p);
    p += dpp_mov<DPP_XOR2>(p);
    return p;
}
__device__ __forceinline__ v2f asv2(double d) { return __builtin_bit_cast(v2f, d); }
__device__ __forceinline__ double asd(v2f v)  { return __builtin_bit_cast(double, v); }

#define PIN8(A) asm volatile("" : "+v"(A[0]), "+v"(A[1]), "+v"(A[2]), "+v"(A[3]), \
                                  "+v"(A[4]), "+v"(A[5]), "+v"(A[6]), "+v"(A[7]))
#define PIN4(A) asm volatile("" : "+v"(A[0]), "+v"(A[1]), "+v"(A[2]), "+v"(A[3]))

// LDS-visibility barrier that does NOT drain vmcnt (keeps table prefetch in flight)
__device__ __forceinline__ void lds_barrier() {
    asm volatile("s_waitcnt lgkmcnt(0)\n\ts_barrier" ::: "memory");
}

// table[v][c] = emb[v,:] @ Wk[:,c] + bias[c]
__global__ __launch_bounds__(256)
void build_table_kernel(const float* __restrict__ emb, const float* __restrict__ Wk,
                        const float* __restrict__ bias, float* __restrict__ table) {
    const int c = threadIdx.x;
    const float bb = bias[c];
    float wcol[EMB];
#pragma unroll
    for (int k = 0; k < EMB; ++k) wcol[k] = Wk[k * FOURH + c];
    for (int v = blockIdx.x; v < VOCAB; v += gridDim.x) {
        const float4* er = (const float4*)(emb + (long)v * EMB);
        float acc = bb;
#pragma unroll
        for (int kk = 0; kk < EMB / 4; ++kk) {
            const float4 e = er[kk];
            acc = fmaf(e.x, wcol[kk * 4 + 0], acc);
            acc = fmaf(e.y, wcol[kk * 4 + 1], acc);
            acc = fmaf(e.z, wcol[kk * 4 + 2], acc);
            acc = fmaf(e.w, wcol[kk * 4 + 3], acc);
        }
        table[(long)v * FOURH + c] = acc;
    }
}

template <bool USE_TABLE>
__global__ __launch_bounds__(256, 2)
void lstm_kernel(const int* __restrict__ tokens, const float* __restrict__ emb,
                 const float* __restrict__ Wk, const float* __restrict__ Wr,
                 const float* __restrict__ bias, const float* __restrict__ Wd,
                 const float* __restrict__ bd, const float* __restrict__ table,
                 float* __restrict__ out)
{
    __shared__ __align__(16) float hbuf[2][HID];
    __shared__ __align__(16) float xbuf[2][EMB];
    __shared__ float lg[NCLS];

    const int tid = threadIdx.x;
    const int w   = tid >> 6;
    const int l   = tid & 63;
    const int q   = l >> 2;
    const int j   = l & 3;              // gate AND k-slice id
    const int u   = (w << 4) + q;       // hidden unit 0..63
    const int seq = blockIdx.x;
    const long tokbase = (long)seq * TSEQ;
    const int colj = u + (j << 6);

    const float m1 = (j == 2) ? 2.0f : 1.0f;   // tanh(g) = 2*sigmoid(2g)-1
    const float m0 = (j == 2) ? -1.0f : 0.0f;
    const float nm1l = -m1 * LOG2E;

    // recurrent weights: 4 cols x 16 k -> 32 double-packed v2f
    double wrd[4][8];
#pragma unroll
    for (int g = 0; g < 4; ++g)
#pragma unroll
        for (int m = 0; m < 8; ++m) {
            const int k = (j << 4) + 2 * m;
            const int cc = u + (g << 6);
            v2f t; t.x = Wr[k * FOURH + cc]; t.y = Wr[(k + 1) * FOURH + cc];
            wrd[g][m] = asd(t);
        }

    double wkd[4][4];
    float bmine = 0.0f;
    if (!USE_TABLE) {
        bmine = bias[colj];
#pragma unroll
        for (int g = 0; g < 4; ++g)
#pragma unroll
            for (int m = 0; m < 4; ++m) {
                const int k = (j << 3) + 2 * m;
                const int cc = u + (g << 6);
                v2f t; t.x = Wk[k * FOURH + cc]; t.y = Wk[(k + 1) * FOURH + cc];
                wkd[g][m] = asd(t);
            }
    }

    if (tid < HID) hbuf[0][tid] = 0.0f;
    float zxA = 0.0f, zxB = 0.0f;
    if (USE_TABLE) {
        const int t0 = tokens[tokbase], t1 = tokens[tokbase + 1];
        zxA = table[(long)t0 * FOURH + colj];
        zxB = table[(long)t1 * FOURH + colj];
    } else {
        if (tid < 8)
            ((float4*)&xbuf[0][0])[tid] = ((const float4*)(emb + (long)tokens[tokbase] * EMB))[tid];
    }
    __syncthreads();

    float c = 0.0f;

    for (int t = 0; t < TSEQ; ++t) {
        const int cur = t & 1, nxt = cur ^ 1;

        // force weight residency every iteration (reload would be >= this cost)
        PIN8(wrd[0]); PIN8(wrd[1]); PIN8(wrd[2]); PIN8(wrd[3]);
        if (!USE_TABLE) { PIN4(wkd[0]); PIN4(wkd[1]); PIN4(wkd[2]); PIN4(wkd[3]); }

        float zxC = 0.0f;
        if (USE_TABLE) {
            const int tn  = (t + 2 < TSEQ) ? t + 2 : TSEQ - 1;
            const int tok = tokens[tokbase + tn];
            zxC = table[(long)tok * FOURH + colj];       // lands at step t+2
        } else {
            const int tn  = (t + 1 < TSEQ) ? t + 1 : TSEQ - 1;
            const int tok = tokens[tokbase + tn];
            if (tid < 8)
                ((float4*)&xbuf[nxt][0])[tid] = ((const float4*)(emb + (long)tok * EMB))[tid];
        }

        const float4* hp = (const float4*)&hbuf[cur][j << 4];
        const float4 h0 = hp[0], h1 = hp[1], h2 = hp[2], h3 = hp[3];
        v2f hh[8];
        hh[0] = (v2f){h0.x, h0.y}; hh[1] = (v2f){h0.z, h0.w};
        hh[2] = (v2f){h1.x, h1.y}; hh[3] = (v2f){h1.z, h1.w};
        hh[4] = (v2f){h2.x, h2.y}; hh[5] = (v2f){h2.z, h2.w};
        hh[6] = (v2f){h3.x, h3.y}; hh[7] = (v2f){h3.z, h3.w};

        v2f a0 = {0.f, 0.f}, a1 = {0.f, 0.f}, a2 = {0.f, 0.f}, a3 = {0.f, 0.f};
#pragma unroll
        for (int m = 0; m < 8; ++m) {
            a0 = __builtin_elementwise_fma(hh[m], asv2(wrd[0][m]), a0);
            a1 = __builtin_elementwise_fma(hh[m], asv2(wrd[1][m]), a1);
            a2 = __builtin_elementwise_fma(hh[m], asv2(wrd[2][m]), a2);
            a3 = __builtin_elementwise_fma(hh[m], asv2(wrd[3][m]), a3);
        }
        if (!USE_TABLE) {
            const float4* xp = (const float4*)&xbuf[cur][j << 3];
            const float4 x0 = xp[0], x1 = xp[1];
            v2f xx[4];
            xx[0] = (v2f){x0.x, x0.y}; xx[1] = (v2f){x0.z, x0.w};
            xx[2] = (v2f){x1.x, x1.y}; xx[3] = (v2f){x1.z, x1.w};
#pragma unroll
            for (int m = 0; m < 4; ++m) {
                a0 = __builtin_elementwise_fma(xx[m], asv2(wkd[0][m]), a0);
                a1 = __builtin_elementwise_fma(xx[m], asv2(wkd[1][m]), a1);
                a2 = __builtin_elementwise_fma(xx[m], asv2(wkd[2][m]), a2);
                a3 = __builtin_elementwise_fma(xx[m], asv2(wkd[3][m]), a3);
            }
        }

        float p0 = qred(a0.x + a0.y);
        float p1 = qred(a1.x + a1.y);
        float p2 = qred(a2.x + a2.y);
        float p3 = qred(a3.x + a3.y);

        float zown = (j < 2) ? ((j == 0) ? p0 : p1) : ((j == 2) ? p2 : p3);
        zown += USE_TABLE ? zxA : bmine;

        const float sg  = __builtin_amdgcn_rcpf(1.0f + __builtin_amdgcn_exp2f(nm1l * zown));
        const float act = fmaf(m1, sg, m0);

        const float gi = dpp_mov<DPP_BC0>(act);
        const float gf = dpp_mov<DPP_BC1>(act);
        const float gg = dpp_mov<DPP_BC2>(act);
        const float go = dpp_mov<DPP_BC3>(act);

        c = fmaf(gf, c, gi * gg);
        const float th = fmaf(2.0f,
            __builtin_amdgcn_rcpf(1.0f + __builtin_amdgcn_exp2f(c * (-2.0f * LOG2E))), -1.0f);
        const float h = go * th;
        if (j == 0) hbuf[nxt][u] = h;

        zxA = zxB; zxB = zxC;
        lds_barrier();          // lgkmcnt-only: table prefetch stays in flight
    }

    const float* hfin = hbuf[TSEQ & 1];
    if (tid < NCLS) {
        float acc = bd[tid];
#pragma unroll 8
        for (int k = 0; k < HID; ++k) acc = fmaf(hfin[k], Wd[k * NCLS + tid], acc);
        lg[tid] = acc;
    }
    __syncthreads();
    if (tid < NCLS) {
        const float l0 = lg[0], l1 = lg[1], l2 = lg[2];
        const float mm = fmaxf(l0, fmaxf(l1, l2));
        const float e0 = __expf(l0 - mm), e1 = __expf(l1 - mm), e2 = __expf(l2 - mm);
        out[seq * NCLS + tid] = __expf(lg[tid] - mm) / (e0 + e1 + e2);
    }
}

extern "C" void kernel_launch(void* const* d_in, const int* in_sizes, int n_in,
                              void* d_out, int out_size, void* d_ws, size_t ws_size,
                              hipStream_t stream) {
    const int*   tokens = (const int*)  d_in[0];
    const float* emb    = (const float*)d_in[1];
    const float* Wk     = (const float*)d_in[2];
    const float* Wr     = (const float*)d_in[3];
    const float* b      = (const float*)d_in[4];
    const float* Wd     = (const float*)d_in[5];
    const float* bd     = (const float*)d_in[6];
    float* out = (float*)d_out;

    const size_t need = (size_t)VOCAB * FOURH * sizeof(float);
    if (ws_size >= need) {
        float* table = (float*)d_ws;
        build_table_kernel<<<dim3(2048), dim3(256), 0, stream>>>(emb, Wk, b, table);
        lstm_kernel<true><<<dim3(BATCH), dim3(256), 0, stream>>>(
            tokens, emb, Wk, Wr, b, Wd, bd, table, out);
    } else {
        lstm_kernel<false><<<dim3(BATCH), dim3(256), 0, stream>>>(
            tokens, emb, Wk, Wr, b, Wd, bd, nullptr, out);
    }
}

// Round 7
// 296.786 us; speedup vs baseline: 1.0341x; 1.0341x over previous
//
#include <hip/hip_runtime.h>

// emb-lookup -> LSTM(64) over T=512 -> Dense(3) -> softmax.  512 blocks x 256 thr.
// Quad = one hidden unit's 4 gate cols (i,f,g,o). Lane j of quad: k-slice
// [16j,16j+16) of h (4 x ds_read_b128, same-addr broadcast = conflict-free),
// partial dots for 4 gate cols via v_pk_fma_f32, quad allreduce + gate
// broadcast via DPP quad_perm. x-projection (+bias) precomputed as
// table[VOCAB][256] in d_ws, prefetched 2 steps ahead.
// R7 KEY CHANGE: amdgpu_waves_per_eu(2,2) (MAX 2 waves/EU). launch_bounds(256,2)
// only constrains min-occupancy; the RA still minimized arch VGPRs (48) and
// homed the 64 weight VGPRs in AGPRs, shuttling v_accvgpr_read/write every
// step (~300 cyc/SIMD/step — the R4/R6 residual). Capping max waves/EU at the
// structural occupancy (grid 512 blocks = 2/CU anyway) makes VGPR frugality
// worthless to the RA -> weights stay VGPR-homed, shuttle gone.
// (R5 lesson: v_pk_fma_f32 cannot encode AGPR sources on gfx950.)
// (R6 lesson: lgkm-only barrier is neutral -- vmcnt drain was not on the
//  critical path; plain __syncthreads restored.)

#define VOCAB 50000
#define EMB 32
#define HID 64
#define NCLS 3
#define BATCH 512
#define TSEQ 512
#define FOURH 256
#define LOG2E 1.4426950408889634f

typedef float v2f __attribute__((ext_vector_type(2)));

#define DPP_XOR1 0xB1  // quad_perm [1,0,3,2]
#define DPP_XOR2 0x4E  // quad_perm [2,3,0,1]
#define DPP_BC0  0x00
#define DPP_BC1  0x55
#define DPP_BC2  0xAA
#define DPP_BC3  0xFF

template <int CTRL>
__device__ __forceinline__ float dpp_mov(float x) {
    int y = __builtin_amdgcn_mov_dpp(__builtin_bit_cast(int, x), CTRL, 0xF, 0xF, true);
    return __builtin_bit_cast(float, y);
}
__device__ __forceinline__ float qred(float p) {
    p += dpp_mov<DPP_XOR1>(p);
    p += dpp_mov<DPP_XOR2>(p);
    return p;
}
__device__ __forceinline__ v2f asv2(double d) { return __builtin_bit_cast(v2f, d); }
__device__ __forceinline__ double asd(v2f v)  { return __builtin_bit_cast(double, v); }

#define PIN8(A) asm volatile("" : "+v"(A[0]), "+v"(A[1]), "+v"(A[2]), "+v"(A[3]), \
                                  "+v"(A[4]), "+v"(A[5]), "+v"(A[6]), "+v"(A[7]))
#define PIN4(A) asm volatile("" : "+v"(A[0]), "+v"(A[1]), "+v"(A[2]), "+v"(A[3]))

// table[v][c] = emb[v,:] @ Wk[:,c] + bias[c]
__global__ __launch_bounds__(256)
void build_table_kernel(const float* __restrict__ emb, const float* __restrict__ Wk,
                        const float* __restrict__ bias, float* __restrict__ table) {
    const int c = threadIdx.x;
    const float bb = bias[c];
    float wcol[EMB];
#pragma unroll
    for (int k = 0; k < EMB; ++k) wcol[k] = Wk[k * FOURH + c];
    for (int v = blockIdx.x; v < VOCAB; v += gridDim.x) {
        const float4* er = (const float4*)(emb + (long)v * EMB);
        float acc = bb;
#pragma unroll
        for (int kk = 0; kk < EMB / 4; ++kk) {
            const float4 e = er[kk];
            acc = fmaf(e.x, wcol[kk * 4 + 0], acc);
            acc = fmaf(e.y, wcol[kk * 4 + 1], acc);
            acc = fmaf(e.z, wcol[kk * 4 + 2], acc);
            acc = fmaf(e.w, wcol[kk * 4 + 3], acc);
        }
        table[(long)v * FOURH + c] = acc;
    }
}

template <bool USE_TABLE>
__global__ __launch_bounds__(256) __attribute__((amdgpu_waves_per_eu(2, 2)))
void lstm_kernel(const int* __restrict__ tokens, const float* __restrict__ emb,
                 const float* __restrict__ Wk, const float* __restrict__ Wr,
                 const float* __restrict__ bias, const float* __restrict__ Wd,
                 const float* __restrict__ bd, const float* __restrict__ table,
                 float* __restrict__ out)
{
    __shared__ __align__(16) float hbuf[2][HID];
    __shared__ __align__(16) float xbuf[2][EMB];
    __shared__ float lg[NCLS];

    const int tid = threadIdx.x;
    const int w   = tid >> 6;
    const int l   = tid & 63;
    const int q   = l >> 2;
    const int j   = l & 3;              // gate AND k-slice id
    const int u   = (w << 4) + q;       // hidden unit 0..63
    const int seq = blockIdx.x;
    const long tokbase = (long)seq * TSEQ;
    const int colj = u + (j << 6);

    const float m1 = (j == 2) ? 2.0f : 1.0f;   // tanh(g) = 2*sigmoid(2g)-1
    const float m0 = (j == 2) ? -1.0f : 0.0f;
    const float nm1l = -m1 * LOG2E;

    // recurrent weights: 4 cols x 16 k -> 32 double-packed v2f
    double wrd[4][8];
#pragma unroll
    for (int g = 0; g < 4; ++g)
#pragma unroll
        for (int m = 0; m < 8; ++m) {
            const int k = (j << 4) + 2 * m;
            const int cc = u + (g << 6);
            v2f t; t.x = Wr[k * FOURH + cc]; t.y = Wr[(k + 1) * FOURH + cc];
            wrd[g][m] = asd(t);
        }

    double wkd[4][4];
    float bmine = 0.0f;
    if (!USE_TABLE) {
        bmine = bias[colj];
#pragma unroll
        for (int g = 0; g < 4; ++g)
#pragma unroll
            for (int m = 0; m < 4; ++m) {
                const int k = (j << 3) + 2 * m;
                const int cc = u + (g << 6);
                v2f t; t.x = Wk[k * FOURH + cc]; t.y = Wk[(k + 1) * FOURH + cc];
                wkd[g][m] = asd(t);
            }
    }

    if (tid < HID) hbuf[0][tid] = 0.0f;
    float zxA = 0.0f, zxB = 0.0f;
    if (USE_TABLE) {
        const int t0 = tokens[tokbase], t1 = tokens[tokbase + 1];
        zxA = table[(long)t0 * FOURH + colj];
        zxB = table[(long)t1 * FOURH + colj];
    } else {
        if (tid < 8)
            ((float4*)&xbuf[0][0])[tid] = ((const float4*)(emb + (long)tokens[tokbase] * EMB))[tid];
    }
    __syncthreads();

    float c = 0.0f;

    for (int t = 0; t < TSEQ; ++t) {
        const int cur = t & 1, nxt = cur ^ 1;

        // force weight residency every iteration (reload would be >= this cost)
        PIN8(wrd[0]); PIN8(wrd[1]); PIN8(wrd[2]); PIN8(wrd[3]);
        if (!USE_TABLE) { PIN4(wkd[0]); PIN4(wkd[1]); PIN4(wkd[2]); PIN4(wkd[3]); }

        float zxC = 0.0f;
        if (USE_TABLE) {
            const int tn  = (t + 2 < TSEQ) ? t + 2 : TSEQ - 1;
            const int tok = tokens[tokbase + tn];
            zxC = table[(long)tok * FOURH + colj];       // lands at step t+2
        } else {
            const int tn  = (t + 1 < TSEQ) ? t + 1 : TSEQ - 1;
            const int tok = tokens[tokbase + tn];
            if (tid < 8)
                ((float4*)&xbuf[nxt][0])[tid] = ((const float4*)(emb + (long)tok * EMB))[tid];
        }

        const float4* hp = (const float4*)&hbuf[cur][j << 4];
        const float4 h0 = hp[0], h1 = hp[1], h2 = hp[2], h3 = hp[3];
        v2f hh[8];
        hh[0] = (v2f){h0.x, h0.y}; hh[1] = (v2f){h0.z, h0.w};
        hh[2] = (v2f){h1.x, h1.y}; hh[3] = (v2f){h1.z, h1.w};
        hh[4] = (v2f){h2.x, h2.y}; hh[5] = (v2f){h2.z, h2.w};
        hh[6] = (v2f){h3.x, h3.y}; hh[7] = (v2f){h3.z, h3.w};

        v2f a0 = {0.f, 0.f}, a1 = {0.f, 0.f}, a2 = {0.f, 0.f}, a3 = {0.f, 0.f};
#pragma unroll
        for (int m = 0; m < 8; ++m) {
            a0 = __builtin_elementwise_fma(hh[m], asv2(wrd[0][m]), a0);
            a1 = __builtin_elementwise_fma(hh[m], asv2(wrd[1][m]), a1);
            a2 = __builtin_elementwise_fma(hh[m], asv2(wrd[2][m]), a2);
            a3 = __builtin_elementwise_fma(hh[m], asv2(wrd[3][m]), a3);
        }
        if (!USE_TABLE) {
            const float4* xp = (const float4*)&xbuf[cur][j << 3];
            const float4 x0 = xp[0], x1 = xp[1];
            v2f xx[4];
            xx[0] = (v2f){x0.x, x0.y}; xx[1] = (v2f){x0.z, x0.w};
            xx[2] = (v2f){x1.x, x1.y}; xx[3] = (v2f){x1.z, x1.w};
#pragma unroll
            for (int m = 0; m < 4; ++m) {
                a0 = __builtin_elementwise_fma(xx[m], asv2(wkd[0][m]), a0);
                a1 = __builtin_elementwise_fma(xx[m], asv2(wkd[1][m]), a1);
                a2 = __builtin_elementwise_fma(xx[m], asv2(wkd[2][m]), a2);
                a3 = __builtin_elementwise_fma(xx[m], asv2(wkd[3][m]), a3);
            }
        }

        float p0 = qred(a0.x + a0.y);
        float p1 = qred(a1.x + a1.y);
        float p2 = qred(a2.x + a2.y);
        float p3 = qred(a3.x + a3.y);

        float zown = (j < 2) ? ((j == 0) ? p0 : p1) : ((j == 2) ? p2 : p3);
        zown += USE_TABLE ? zxA : bmine;

        const float sg  = __builtin_amdgcn_rcpf(1.0f + __builtin_amdgcn_exp2f(nm1l * zown));
        const float act = fmaf(m1, sg, m0);

        const float gi = dpp_mov<DPP_BC0>(act);
        const float gf = dpp_mov<DPP_BC1>(act);
        const float gg = dpp_mov<DPP_BC2>(act);
        const float go = dpp_mov<DPP_BC3>(act);

        c = fmaf(gf, c, gi * gg);
        const float th = fmaf(2.0f,
            __builtin_amdgcn_rcpf(1.0f + __builtin_amdgcn_exp2f(c * (-2.0f * LOG2E))), -1.0f);
        const float h = go * th;
        if (j == 0) hbuf[nxt][u] = h;

        zxA = zxB; zxB = zxC;
        __syncthreads();
    }

    const float* hfin = hbuf[TSEQ & 1];
    if (tid < NCLS) {
        float acc = bd[tid];
#pragma unroll 8
        for (int k = 0; k < HID; ++k) acc = fmaf(hfin[k], Wd[k * NCLS + tid], acc);
        lg[tid] = acc;
    }
    __syncthreads();
    if (tid < NCLS) {
        const float l0 = lg[0], l1 = lg[1], l2 = lg[2];
        const float mm = fmaxf(l0, fmaxf(l1, l2));
        const float e0 = __expf(l0 - mm), e1 = __expf(l1 - mm), e2 = __expf(l2 - mm);
        out[seq * NCLS + tid] = __expf(lg[tid] - mm) / (e0 + e1 + e2);
    }
}

extern "C" void kernel_launch(void* const* d_in, const int* in_sizes, int n_in,
                              void* d_out, int out_size, void* d_ws, size_t ws_size,
                              hipStream_t stream) {
    const int*   tokens = (const int*)  d_in[0];
    const float* emb    = (const float*)d_in[1];
    const float* Wk     = (const float*)d_in[2];
    const float* Wr     = (const float*)d_in[3];
    const float* b      = (const float*)d_in[4];
    const float* Wd     = (const float*)d_in[5];
    const float* bd     = (const float*)d_in[6];
    float* out = (float*)d_out;

    const size_t need = (size_t)VOCAB * FOURH * sizeof(float);
    if (ws_size >= need) {
        float* table = (float*)d_ws;
        build_table_kernel<<<dim3(2048), dim3(256), 0, stream>>>(emb, Wk, b, table);
        lstm_kernel<true><<<dim3(BATCH), dim3(256), 0, stream>>>(
            tokens, emb, Wk, Wr, b, Wd, bd, table, out);
    } else {
        lstm_kernel<false><<<dim3(BATCH), dim3(256), 0, stream>>>(
            tokens, emb, Wk, Wr, b, Wd, bd, nullptr, out);
    }
}

// Round 8
// 288.187 us; speedup vs baseline: 1.0650x; 1.0298x over previous
//
#include <hip/hip_runtime.h>

// emb-lookup -> LSTM(64) over T=512 -> Dense(3) -> softmax.  512 blocks x 256 thr.
// Quad = one hidden unit's 4 gate cols (i,f,g,o). Lane j of quad: k-slice
// [16j,16j+16) of h, partial dots for 4 gate cols via v_dot2_f32_f16 with
// fp16 weights (32 half2 regs) and fp16 h hand-off in LDS (2 x ds_read_b128
// broadcast). Quad allreduce + gate broadcast via DPP quad_perm. c/gates/table
// all fp32. x-projection (+bias) precomputed as table[VOCAB][256] in d_ws,
// prefetched 2 steps ahead.
// R8 rationale: R7 still issued ~156 instr/lane/step (VALUBusy 58% @ 1078
// cyc/step) vs ~75 real -- residual = AGPR shuttle for the half of the 64
// f32 weight VGPRs the RA would not home in VGPRs (VGPR_Count 88 < ~108
// needed) + v2f repack movs + pair-adds. fp16 dot2 shrinks weights to 32
// regs (no shuttle possible), kills pair-adds and repacks, halves h reads.
// (R5: v_pk_fma_f32 can't encode AGPR srcs. R6: lgkm-only barrier neutral.)

#define VOCAB 50000
#define EMB 32
#define HID 64
#define NCLS 3
#define BATCH 512
#define TSEQ 512
#define FOURH 256
#define LOG2E 1.4426950408889634f

typedef _Float16 v2h __attribute__((ext_vector_type(2)));

#define DPP_XOR1 0xB1  // quad_perm [1,0,3,2]
#define DPP_XOR2 0x4E  // quad_perm [2,3,0,1]
#define DPP_BC0  0x00
#define DPP_BC1  0x55
#define DPP_BC2  0xAA
#define DPP_BC3  0xFF

template <int CTRL>
__device__ __forceinline__ float dpp_mov(float x) {
    int y = __builtin_amdgcn_mov_dpp(__builtin_bit_cast(int, x), CTRL, 0xF, 0xF, true);
    return __builtin_bit_cast(float, y);
}
__device__ __forceinline__ float qred(float p) {
    p += dpp_mov<DPP_XOR1>(p);
    p += dpp_mov<DPP_XOR2>(p);
    return p;
}
__device__ __forceinline__ v2h bch(int i)   { return __builtin_bit_cast(v2h, i); }
__device__ __forceinline__ v2h bchf(float f){ return __builtin_bit_cast(v2h, f); }

#define PIN8(A) asm volatile("" : "+v"(A[0]), "+v"(A[1]), "+v"(A[2]), "+v"(A[3]), \
                                  "+v"(A[4]), "+v"(A[5]), "+v"(A[6]), "+v"(A[7]))

// table[v][c] = emb[v,:] @ Wk[:,c] + bias[c]
__global__ __launch_bounds__(256)
void build_table_kernel(const float* __restrict__ emb, const float* __restrict__ Wk,
                        const float* __restrict__ bias, float* __restrict__ table) {
    const int c = threadIdx.x;
    const float bb = bias[c];
    float wcol[EMB];
#pragma unroll
    for (int k = 0; k < EMB; ++k) wcol[k] = Wk[k * FOURH + c];
    for (int v = blockIdx.x; v < VOCAB; v += gridDim.x) {
        const float4* er = (const float4*)(emb + (long)v * EMB);
        float acc = bb;
#pragma unroll
        for (int kk = 0; kk < EMB / 4; ++kk) {
            const float4 e = er[kk];
            acc = fmaf(e.x, wcol[kk * 4 + 0], acc);
            acc = fmaf(e.y, wcol[kk * 4 + 1], acc);
            acc = fmaf(e.z, wcol[kk * 4 + 2], acc);
            acc = fmaf(e.w, wcol[kk * 4 + 3], acc);
        }
        table[(long)v * FOURH + c] = acc;
    }
}

template <bool USE_TABLE>
__global__ __launch_bounds__(256) __attribute__((amdgpu_waves_per_eu(2, 2)))
void lstm_kernel(const int* __restrict__ tokens, const float* __restrict__ emb,
                 const float* __restrict__ Wk, const float* __restrict__ Wr,
                 const float* __restrict__ bias, const float* __restrict__ Wd,
                 const float* __restrict__ bd, const float* __restrict__ table,
                 float* __restrict__ out)
{
    __shared__ __align__(16) _Float16 hbuf[2][HID];   // fp16 h hand-off
    __shared__ __align__(16) float xbuf[2][EMB];
    __shared__ float lg[NCLS];

    const int tid = threadIdx.x;
    const int w   = tid >> 6;
    const int l   = tid & 63;
    const int q   = l >> 2;
    const int j   = l & 3;              // gate AND k-slice id
    const int u   = (w << 4) + q;       // hidden unit 0..63
    const int seq = blockIdx.x;
    const long tokbase = (long)seq * TSEQ;
    const int colj = u + (j << 6);

    const float m1 = (j == 2) ? 2.0f : 1.0f;   // tanh(g) = 2*sigmoid(2g)-1
    const float m0 = (j == 2) ? -1.0f : 0.0f;
    const float nm1l = -m1 * LOG2E;

    // recurrent weights: 4 cols x 16 k -> 32 half2 (int-packed for pinning)
    int wrh[4][8];
#pragma unroll
    for (int g = 0; g < 4; ++g)
#pragma unroll
        for (int m = 0; m < 8; ++m) {
            const int k = (j << 4) + 2 * m;
            const int cc = u + (g << 6);
            v2h t;
            t.x = (_Float16)Wr[k * FOURH + cc];
            t.y = (_Float16)Wr[(k + 1) * FOURH + cc];
            wrh[g][m] = __builtin_bit_cast(int, t);
        }

    float wkf[4][8];          // fallback x-weights (f32 scalar path)
    float bmine = 0.0f;
    if (!USE_TABLE) {
        bmine = bias[colj];
#pragma unroll
        for (int g = 0; g < 4; ++g)
#pragma unroll
            for (int m = 0; m < 8; ++m)
                wkf[g][m] = Wk[((j << 3) + m) * FOURH + (u + (g << 6))];
    }

    if (tid < HID) hbuf[0][tid] = (_Float16)0.0f;
    float zxA = 0.0f, zxB = 0.0f;
    if (USE_TABLE) {
        const int t0 = tokens[tokbase], t1 = tokens[tokbase + 1];
        zxA = table[(long)t0 * FOURH + colj];
        zxB = table[(long)t1 * FOURH + colj];
    } else {
        if (tid < 8)
            ((float4*)&xbuf[0][0])[tid] = ((const float4*)(emb + (long)tokens[tokbase] * EMB))[tid];
    }
    __syncthreads();

    float c = 0.0f;

    for (int t = 0; t < TSEQ; ++t) {
        const int cur = t & 1, nxt = cur ^ 1;

        // force weight residency every iteration
        PIN8(wrh[0]); PIN8(wrh[1]); PIN8(wrh[2]); PIN8(wrh[3]);

        float zxC = 0.0f;
        if (USE_TABLE) {
            const int tn  = (t + 2 < TSEQ) ? t + 2 : TSEQ - 1;
            const int tok = tokens[tokbase + tn];
            zxC = table[(long)tok * FOURH + colj];       // lands at step t+2
        } else {
            const int tn  = (t + 1 < TSEQ) ? t + 1 : TSEQ - 1;
            const int tok = tokens[tokbase + tn];
            if (tid < 8)
                ((float4*)&xbuf[nxt][0])[tid] = ((const float4*)(emb + (long)tok * EMB))[tid];
        }

        // h slice [16j,16j+16) as 8 half2: two 16B broadcast reads
        const float4* hp = (const float4*)&hbuf[cur][j << 4];
        const float4 H0 = hp[0], H1 = hp[1];
        v2h h2[8];
        h2[0] = bchf(H0.x); h2[1] = bchf(H0.y); h2[2] = bchf(H0.z); h2[3] = bchf(H0.w);
        h2[4] = bchf(H1.x); h2[5] = bchf(H1.y); h2[6] = bchf(H1.z); h2[7] = bchf(H1.w);

        float p0 = 0.f, p1 = 0.f, p2 = 0.f, p3 = 0.f;
#pragma unroll
        for (int m = 0; m < 8; ++m) {
            p0 = __builtin_amdgcn_fdot2(h2[m], bch(wrh[0][m]), p0, false);
            p1 = __builtin_amdgcn_fdot2(h2[m], bch(wrh[1][m]), p1, false);
            p2 = __builtin_amdgcn_fdot2(h2[m], bch(wrh[2][m]), p2, false);
            p3 = __builtin_amdgcn_fdot2(h2[m], bch(wrh[3][m]), p3, false);
        }
        if (!USE_TABLE) {
            const float* xp = &xbuf[cur][j << 3];
#pragma unroll
            for (int m = 0; m < 8; ++m) {
                const float xm = xp[m];
                p0 = fmaf(xm, wkf[0][m], p0);
                p1 = fmaf(xm, wkf[1][m], p1);
                p2 = fmaf(xm, wkf[2][m], p2);
                p3 = fmaf(xm, wkf[3][m], p3);
            }
        }

        p0 = qred(p0); p1 = qred(p1); p2 = qred(p2); p3 = qred(p3);

        float zown = (j < 2) ? ((j == 0) ? p0 : p1) : ((j == 2) ? p2 : p3);
        zown += USE_TABLE ? zxA : bmine;

        const float sg  = __builtin_amdgcn_rcpf(1.0f + __builtin_amdgcn_exp2f(nm1l * zown));
        const float act = fmaf(m1, sg, m0);

        const float gi = dpp_mov<DPP_BC0>(act);
        const float gf = dpp_mov<DPP_BC1>(act);
        const float gg = dpp_mov<DPP_BC2>(act);
        const float go = dpp_mov<DPP_BC3>(act);

        c = fmaf(gf, c, gi * gg);
        const float th = fmaf(2.0f,
            __builtin_amdgcn_rcpf(1.0f + __builtin_amdgcn_exp2f(c * (-2.0f * LOG2E))), -1.0f);
        const float h = go * th;
        if (j == 0) hbuf[nxt][u] = (_Float16)h;

        zxA = zxB; zxB = zxC;
        __syncthreads();
    }

    const _Float16* hfin = hbuf[TSEQ & 1];
    if (tid < NCLS) {
        float acc = bd[tid];
#pragma unroll 8
        for (int k = 0; k < HID; ++k) acc = fmaf((float)hfin[k], Wd[k * NCLS + tid], acc);
        lg[tid] = acc;
    }
    __syncthreads();
    if (tid < NCLS) {
        const float l0 = lg[0], l1 = lg[1], l2 = lg[2];
        const float mm = fmaxf(l0, fmaxf(l1, l2));
        const float e0 = __expf(l0 - mm), e1 = __expf(l1 - mm), e2 = __expf(l2 - mm);
        out[seq * NCLS + tid] = __expf(lg[tid] - mm) / (e0 + e1 + e2);
    }
}

extern "C" void kernel_launch(void* const* d_in, const int* in_sizes, int n_in,
                              void* d_out, int out_size, void* d_ws, size_t ws_size,
                              hipStream_t stream) {
    const int*   tokens = (const int*)  d_in[0];
    const float* emb    = (const float*)d_in[1];
    const float* Wk     = (const float*)d_in[2];
    const float* Wr     = (const float*)d_in[3];
    const float* b      = (const float*)d_in[4];
    const float* Wd     = (const float*)d_in[5];
    const float* bd     = (const float*)d_in[6];
    float* out = (float*)d_out;

    const size_t need = (size_t)VOCAB * FOURH * sizeof(float);
    if (ws_size >= need) {
        float* table = (float*)d_ws;
        build_table_kernel<<<dim3(2048), dim3(256), 0, stream>>>(emb, Wk, b, table);
        lstm_kernel<true><<<dim3(BATCH), dim3(256), 0, stream>>>(
            tokens, emb, Wk, Wr, b, Wd, bd, table, out);
    } else {
        lstm_kernel<false><<<dim3(BATCH), dim3(256), 0, stream>>>(
            tokens, emb, Wk, Wr, b, Wd, bd, nullptr, out);
    }
}